// Round 12
// baseline (102.753 us; speedup 1.0000x reference)
//
#include <hip/hip_runtime.h>

typedef __attribute__((ext_vector_type(8))) short short8;
typedef __attribute__((ext_vector_type(4))) float float4v;

// win(i) = clamped 4-wide tile window [LOW[i], HIW[i]] (H=16, PART=4).
// Padded to 24 entries with never-true sentinels so the fixed 8-trip padded
// ct-loop can index LOW/HIW with raw ct (<= 17) and get FALSE conditions.
__constant__ int LOW[24] = {0,0,0,1,2,3,4,5,6,7,8,9,10,11,12,12,
                            99,99,99,99,99,99,99,99};
__constant__ int HIW[24] = {3,3,3,4,5,6,7,8,9,10,11,12,13,14,15,15,
                            -1,-1,-1,-1,-1,-1,-1,-1};
// Per-wave ct-loop start: wave w owns row-tiles rt=4w..4w+3; its union ct range
// (s2: ct in win(rt); s1: rt in win(ct)) fits in [CTLO[w], CTLO[w]+7].
__constant__ int CTLO[4] = {0, 2, 6, 10};

__device__ __forceinline__ unsigned short f2bf(float f) {
    unsigned int x = __builtin_bit_cast(unsigned int, f);
    x += 0x7FFF + ((x >> 16) & 1);   // round-to-nearest-even
    return (unsigned short)(x >> 16);
}

struct __align__(16) U16x8 { unsigned short u[8]; };

// DPP cross-lane ops within 16-lane rows — pure VALU, no LDS pipe.
template <int CTRL>
__device__ __forceinline__ float dppmaxf(float x) {
    int y = __builtin_amdgcn_update_dpp(0, __builtin_bit_cast(int, x),
                                        CTRL, 0xF, 0xF, true);
    return fmaxf(x, __builtin_bit_cast(float, y));
}
template <int CTRL>
__device__ __forceinline__ float dppaddf(float x) {
    int y = __builtin_amdgcn_update_dpp(0, __builtin_bit_cast(int, x),
                                        CTRL, 0xF, 0xF, true);
    return x + __builtin_bit_cast(float, y);
}
// XOR-pairing butterflies (xor1, xor2, xor4, xor8 within 16): valid for max&sum.
__device__ __forceinline__ float rowmax16(float x) {
    x = dppmaxf<0xB1>(x);    // quad_perm [1,0,3,2]
    x = dppmaxf<0x4E>(x);    // quad_perm [2,3,0,1]
    x = dppmaxf<0x141>(x);   // row_half_mirror
    x = dppmaxf<0x140>(x);   // row_mirror
    return x;
}
__device__ __forceinline__ float rowsum16(float x) {
    x = dppaddf<0xB1>(x);
    x = dppaddf<0x4E>(x);
    x = dppaddf<0x141>(x);
    x = dppaddf<0x140>(x);
    return x;
}

// Kernel 0: f32 [img][64c][256s] -> bf16 [img][s][c] with chunk XOR swizzle
// (chunk' = (c/8) ^ (s%8)). imgs 0..47 = probe, 48..95 = gallery.
// 384 single-wave blocks (img = bid>>2, s-quarter = bid&3): spreads the
// HBM-cold input read across 384 waves instead of 96 fat blocks on 96 CUs.
__global__ __launch_bounds__(64) void pretranspose_kernel(
    const float* __restrict__ prob,
    const float* __restrict__ gal,
    unsigned short* __restrict__ outT)   // [96][16384] bf16
{
    const int img = blockIdx.x >> 2;
    const int quarter = blockIdx.x & 3;
    const float* src = (img < 48) ? (prob + img * 16384)
                                  : (gal + (img - 48) * 16384);
    unsigned short* dst = outT + img * 16384;
    const int tid = threadIdx.x;          // 0..63
    const int c0 = (tid & 7) * 8;
    const int s0 = quarter * 64 + (tid >> 3) * 8;
    unsigned short v[8][8];
#pragma unroll
    for (int i = 0; i < 8; ++i) {
        const float* p = src + (c0 + i) * 256 + s0;
        const float4v f0 = *(const float4v*)(p);
        const float4v f1 = *(const float4v*)(p + 4);
        v[i][0] = f2bf(f0.x); v[i][1] = f2bf(f0.y);
        v[i][2] = f2bf(f0.z); v[i][3] = f2bf(f0.w);
        v[i][4] = f2bf(f1.x); v[i][5] = f2bf(f1.y);
        v[i][6] = f2bf(f1.z); v[i][7] = f2bf(f1.w);
    }
#pragma unroll
    for (int j = 0; j < 8; ++j) {
        U16x8 o;
#pragma unroll
        for (int i = 0; i < 8; ++i) o.u[i] = v[i][j];
        const int srow = s0 + j;
        const int off = srow * 64 + (((c0 >> 3) ^ (srow & 7)) << 3);
        *(U16x8*)(dst + off) = o;
    }
}

// Kernel A: one block per (probe, 3-gallery group): grid 768 = 3 blocks/CU,
// one dispatch round. B-fragments (probe) loaded once per block. The 3-pair
// loop is fully unrolled and SOFTWARE-PIPELINED across pairs: pair k+1's
// A-fragment loads issue right after pair k's MFMA section, so their L2
// latency overlaps pair k's epilogue (rowmax + LDS merge + barriers) — the
// intra-pair serial path that R3-R11 never broke.
// acc.i = score(r = rt*16 + q*4 + i, s = ct*16 + laneM).
__global__ __launch_bounds__(256, 3) void score_pam_kernel(
    const unsigned short* __restrict__ preT,  // [96][16384] bf16 pre-transposed
    const float* __restrict__ fcw,            // [256] f32
    float* __restrict__ outDot,               // [2304]
    float* __restrict__ outSum,               // [2304]
    float* __restrict__ outSq)                // [2304]
{
    __shared__ float s1part[4][8][4][16];      // (w, i, q, col) 8 KB
    __shared__ float redA[4][4][4];            // s2: (w, q, {dot,sum,sq,pad})
    __shared__ float redB[4][4];               // s1: (w, {dot,sum,sq,pad})

    const int tid = threadIdx.x;
    const int ip = blockIdx.x >> 4;            // probe index (0..47)
    const int grp = blockIdx.x & 15;           // gallery group (0..15)
    const unsigned short* pimg = preT + ip * 16384;   // B: probe (cols)

    const int lane = tid & 63;
    const int w = tid >> 6;
    const int laneM = lane & 15;
    const int q = lane >> 4;
    const int z = laneM & 7;

    const int rtb = 4 * w;
    int lo2[4], hi2[4];
#pragma unroll
    for (int j = 0; j < 4; ++j) { lo2[j] = LOW[rtb + j]; hi2[j] = HIW[rtb + j]; }
    const int ctbase = CTLO[w];

    // ---- B-fragments: ONCE per block, reused for all 3 gallery pairs
    short8 B0[8], B1[8];
#pragma unroll
    for (int i = 0; i < 8; ++i) {
        const int ctr = ctbase + i;
        const int ctc = (ctr > 15) ? 15 : ctr;   // clamp address only
        const int sl = ctc * 16 + laneM;
        B0[i] = *(const short8*)(pimg + sl * 64 + ((q ^ z) << 3));
        B1[i] = *(const short8*)(pimg + sl * 64 + (((q + 4) ^ z) << 3));
    }
    // fc_w fragments (kept-row weights), once per block
    float4v fw[4];
#pragma unroll
    for (int j = 0; j < 4; ++j)
        fw[j] = *(const float4v*)(fcw + (rtb + j) * 16 + q * 4);
    const float fcw_t = fcw[tid];              // for the s1 merge

    // ---- prologue: A-fragments for pair k=0
    short8 a0[4], a1[4];
#pragma unroll
    for (int j = 0; j < 4; ++j) {
        const int srow = (rtb + j) * 16 + laneM;
        const unsigned short* g0 = preT + (48 + 3 * grp) * 16384;
        a0[j] = *(const short8*)(g0 + srow * 64 + ((q ^ z) << 3));
        a1[j] = *(const short8*)(g0 + srow * 64 + (((q + 4) ^ z) << 3));
    }

#pragma unroll
    for (int k = 0; k < 3; ++k) {
        const int ig = 3 * grp + k;
        const int pair = ip * 48 + ig;

        float4v run[4];
#pragma unroll
        for (int j = 0; j < 4; ++j)
            run[j] = (float4v){ -3.0e38f, -3.0e38f, -3.0e38f, -3.0e38f };
        float s1p[8];
#pragma unroll
        for (int i = 0; i < 8; ++i) s1p[i] = -3.0e38f;

        // ---- compute: conditions on RAW ct (sentinel rows kill padded trips)
#pragma unroll
        for (int i = 0; i < 8; ++i) {
            const int ctr = ctbase + i;
            const int wl = LOW[ctr], wh = HIW[ctr];
#pragma unroll
            for (int j = 0; j < 4; ++j) {
                const int rt = rtb + j;
                const bool c2 = (ctr >= lo2[j]) && (ctr <= hi2[j]);  // hc in win(hr)
                const bool c1 = (rt >= wl) && (rt <= wh);            // hr in win(hc)
                if (c1 || c2) {
                    float4v acc = { 0.f, 0.f, 0.f, 0.f };
                    acc = __builtin_amdgcn_mfma_f32_16x16x32_bf16(a0[j], B0[i], acc, 0, 0, 0);
                    acc = __builtin_amdgcn_mfma_f32_16x16x32_bf16(a1[j], B1[i], acc, 0, 0, 0);
                    if (c2) {   // s2: per-row running max
                        run[j].x = fmaxf(run[j].x, acc.x);
                        run[j].y = fmaxf(run[j].y, acc.y);
                        run[j].z = fmaxf(run[j].z, acc.z);
                        run[j].w = fmaxf(run[j].w, acc.w);
                    }
                    if (c1) {   // s1: quad-partial col-max
                        const float t = fmaxf(fmaxf(acc.x, acc.y), fmaxf(acc.z, acc.w));
                        s1p[i] = fmaxf(s1p[i], t);
                    }
                }
            }
        }

        // ---- PIPELINE: issue pair k+1's A-loads now, before the epilogue.
        // Their L2 latency (~300-600 cyc) overlaps rowmax+barriers+merge below.
        // Last pair reloads its own image (L1-hot duplicate, harmless).
        {
            const int ign = 3 * grp + ((k < 2) ? (k + 1) : k);
            const unsigned short* gn = preT + (48 + ign) * 16384;
#pragma unroll
            for (int j = 0; j < 4; ++j) {
                const int srow = (rtb + j) * 16 + laneM;
                a0[j] = *(const short8*)(gn + srow * 64 + ((q ^ z) << 3));
                a1[j] = *(const short8*)(gn + srow * 64 + (((q + 4) ^ z) << 3));
            }
        }

        // ---- s2 epilogue: DPP row-max + masked register accumulation
        float dot = 0.f, sum = 0.f, sq = 0.f;
        const float msk = (laneM == 0) ? 1.0f : 0.0f;   // count each row once
#pragma unroll
        for (int j = 0; j < 4; ++j) {
            const float rx = rowmax16(run[j].x);
            const float ry = rowmax16(run[j].y);
            const float rz = rowmax16(run[j].z);
            const float rw = rowmax16(run[j].w);
            float t;
            t = msk * rx; dot += t * fw[j].x; sum += t; sq += t * rx;
            t = msk * ry; dot += t * fw[j].y; sum += t; sq += t * ry;
            t = msk * rz; dot += t * fw[j].z; sum += t; sq += t * rz;
            t = msk * rw; dot += t * fw[j].w; sum += t; sq += t * rw;
        }

        __syncthreads();   // previous pair's s1part/redA/redB readers are done
        if (laneM == 0) { redA[w][q][0] = dot; redA[w][q][1] = sum; redA[w][q][2] = sq; }
#pragma unroll
        for (int i = 0; i < 8; ++i) s1part[w][i][q][laneM] = s1p[i];
        __syncthreads();   // s1part/redA published

        // ---- s1 merge: thread tid <-> (hc = tid>>4, col = tid&15)
        {
            const int hc = tid >> 4;
            const int col = tid & 15;
            float v = -3.0e38f;
#pragma unroll
            for (int wv = 0; wv < 4; ++wv) {
                const int ii = hc - CTLO[wv];
                if (ii >= 0 && ii < 8) {
#pragma unroll
                    for (int q2 = 0; q2 < 4; ++q2)
                        v = fmaxf(v, s1part[wv][ii][q2][col]);
                }
            }
            // sum over the 16 cols (DPP), then the wave's 4 hc-groups (shfl)
            float d1 = rowsum16(v * fcw_t);
            float s1v = rowsum16(v);
            float q1 = rowsum16(v * v);
            d1 += __shfl_xor(d1, 16, 64);  s1v += __shfl_xor(s1v, 16, 64);
            q1 += __shfl_xor(q1, 16, 64);
            d1 += __shfl_xor(d1, 32, 64);  s1v += __shfl_xor(s1v, 32, 64);
            q1 += __shfl_xor(q1, 32, 64);
            if (lane == 0) { redB[w][0] = d1; redB[w][1] = s1v; redB[w][2] = q1; }
        }
        __syncthreads();   // redB published

        if (tid < 3) {
            float s = 0.f;
#pragma unroll
            for (int a = 0; a < 4; ++a) {
#pragma unroll
                for (int b = 0; b < 4; ++b) s += redA[a][b][tid];
                s += redB[a][tid];
            }
            if (tid == 0) outDot[pair] = s;
            else if (tid == 1) outSum[pair] = s;
            else outSq[pair] = s;
        }
    }
}

// Kernel B: single block. Global BN1 stats from per-pair sums, fc (linear),
// pair-sum, BN2 over 2304, sigmoid, f32 store.
__global__ __launch_bounds__(256) void finalize_kernel(
    const float* __restrict__ dDot,
    const float* __restrict__ dSum,
    const float* __restrict__ dSq,
    const float* __restrict__ bng,
    const float* __restrict__ bnb,
    const float* __restrict__ fcw,
    const float* __restrict__ fcb,
    const float* __restrict__ lg,
    const float* __restrict__ lb,
    float* __restrict__ outp)   // [2304] f32
{
    __shared__ float red[12];
    const int tid = threadIdx.x;
    const int lane = tid & 63;
    const int w = tid >> 6;

    float S = 0.f, Q = 0.f;
    float dv[9];
#pragma unroll
    for (int k = 0; k < 9; ++k) {
        const int i = tid + 256 * k;
        dv[k] = dDot[i];
        S += dSum[i];
        Q += dSq[i];
    }
    float Wj = fcw[tid];
#pragma unroll
    for (int d = 32; d >= 1; d >>= 1) {
        S += __shfl_down(S, d, 64);
        Q += __shfl_down(Q, d, 64);
        Wj += __shfl_down(Wj, d, 64);
    }
    if (lane == 0) { red[w] = S; red[4 + w] = Q; red[8 + w] = Wj; }
    __syncthreads();
    S = red[0] + red[1] + red[2] + red[3];
    Q = red[4] + red[5] + red[6] + red[7];
    const float W = red[8] + red[9] + red[10] + red[11];
    __syncthreads();

    const float N1 = 1179648.0f;           // 4608 * 256 elements in BN1
    const float m1 = S / N1;
    const float v1 = Q / N1 - m1 * m1;     // biased var (torch training default)
    const float inv1 = rsqrtf(v1 + 1e-5f);
    const float g1 = bng[0], b1 = bnb[0], fb = fcb[0];
    const float g2 = lg[0], b2 = lb[0];
    const float cA = g1 * inv1;
    const float cB = 2.f * (b1 * W + fb) - cA * 2.f * m1 * W;

    float Sy = 0.f, Qy = 0.f;
    float yv[9];
#pragma unroll
    for (int k = 0; k < 9; ++k) {
        const float y = cA * dv[k] + cB;
        yv[k] = y;
        Sy += y;
        Qy += y * y;
    }
#pragma unroll
    for (int d = 32; d >= 1; d >>= 1) {
        Sy += __shfl_down(Sy, d, 64);
        Qy += __shfl_down(Qy, d, 64);
    }
    if (lane == 0) { red[w] = Sy; red[4 + w] = Qy; }
    __syncthreads();
    Sy = red[0] + red[1] + red[2] + red[3];
    Qy = red[4] + red[5] + red[6] + red[7];

    const float m2 = Sy / 2304.0f;
    const float v2 = Qy / 2304.0f - m2 * m2;
    const float inv2 = rsqrtf(v2 + 1e-5f);
#pragma unroll
    for (int k = 0; k < 9; ++k) {
        const int i = tid + 256 * k;
        const float z = g2 * (yv[k] - m2) * inv2 + b2;
        outp[i] = 1.0f / (1.0f + __expf(-z));
    }
}

extern "C" void kernel_launch(void* const* d_in, const int* in_sizes, int n_in,
                              void* d_out, int out_size, void* d_ws, size_t ws_size,
                              hipStream_t stream) {
    const float* prob = (const float*)d_in[0];
    const float* gal  = (const float*)d_in[1];
    const float* bng  = (const float*)d_in[2];
    const float* bnb  = (const float*)d_in[3];
    const float* fcw  = (const float*)d_in[4];
    const float* fcb  = (const float*)d_in[5];
    const float* lg   = (const float*)d_in[6];
    const float* lb   = (const float*)d_in[7];

    unsigned short* preT = (unsigned short*)d_ws;        // 96*16384 bf16 = 3 MB
    float* ws = (float*)((char*)d_ws + 96 * 16384 * sizeof(unsigned short));
    float* dDot = ws;            // [2304]
    float* dSum = ws + 2304;     // [2304]
    float* dSq  = ws + 4608;     // [2304]

    hipLaunchKernelGGL(pretranspose_kernel, dim3(384), dim3(64), 0, stream,
                       prob, gal, preT);
    hipLaunchKernelGGL(score_pam_kernel, dim3(768), dim3(256), 0, stream,
                       preT, fcw, dDot, dSum, dSq);
    hipLaunchKernelGGL(finalize_kernel, dim3(1), dim3(256), 0, stream,
                       dDot, dSum, dSq, bng, bnb, fcw, fcb, lg, lb,
                       (float*)d_out);
}

// Round 13
// 95.364 us; speedup vs baseline: 1.0775x; 1.0775x over previous
//
#include <hip/hip_runtime.h>

typedef __attribute__((ext_vector_type(8))) short short8;
typedef __attribute__((ext_vector_type(4))) float float4v;

__device__ __forceinline__ unsigned short f2bf(float f) {
    unsigned int x = __builtin_bit_cast(unsigned int, f);
    x += 0x7FFF + ((x >> 16) & 1);   // round-to-nearest-even
    return (unsigned short)(x >> 16);
}

struct __align__(16) U16x8 { unsigned short u[8]; };

// DPP cross-lane ops within 16-lane rows — pure VALU.
template <int CTRL>
__device__ __forceinline__ float dppmaxf(float x) {
    int y = __builtin_amdgcn_update_dpp(0, __builtin_bit_cast(int, x),
                                        CTRL, 0xF, 0xF, true);
    return fmaxf(x, __builtin_bit_cast(float, y));
}
template <int CTRL>
__device__ __forceinline__ float dppaddf(float x) {
    int y = __builtin_amdgcn_update_dpp(0, __builtin_bit_cast(int, x),
                                        CTRL, 0xF, 0xF, true);
    return x + __builtin_bit_cast(float, y);
}
__device__ __forceinline__ float rowmax16(float x) {
    x = dppmaxf<0xB1>(x);    // quad_perm [1,0,3,2]
    x = dppmaxf<0x4E>(x);    // quad_perm [2,3,0,1]
    x = dppmaxf<0x141>(x);   // row_half_mirror
    x = dppmaxf<0x140>(x);   // row_mirror
    return x;
}
__device__ __forceinline__ float rowsum16(float x) {
    x = dppaddf<0xB1>(x);
    x = dppaddf<0x4E>(x);
    x = dppaddf<0x141>(x);
    x = dppaddf<0x140>(x);
    return x;
}

// Kernel 0: f32 [img][64c][256s] -> bf16 [img][s][c] with chunk XOR swizzle
// (chunk' = (c/8) ^ (s%8)). imgs 0..47 = probe, 48..95 = gallery.
// 384 single-wave blocks: img = bid>>2, s-quarter = bid&3.
__global__ __launch_bounds__(64) void pretranspose_kernel(
    const float* __restrict__ prob,
    const float* __restrict__ gal,
    unsigned short* __restrict__ outT)   // [96][16384] bf16
{
    const int img = blockIdx.x >> 2;
    const int quarter = blockIdx.x & 3;
    const float* src = (img < 48) ? (prob + img * 16384)
                                  : (gal + (img - 48) * 16384);
    unsigned short* dst = outT + img * 16384;
    const int tid = threadIdx.x;          // 0..63
    const int c0 = (tid & 7) * 8;
    const int s0 = quarter * 64 + (tid >> 3) * 8;
    unsigned short v[8][8];
#pragma unroll
    for (int i = 0; i < 8; ++i) {
        const float* p = src + (c0 + i) * 256 + s0;
        const float4v f0 = *(const float4v*)(p);
        const float4v f1 = *(const float4v*)(p + 4);
        v[i][0] = f2bf(f0.x); v[i][1] = f2bf(f0.y);
        v[i][2] = f2bf(f0.z); v[i][3] = f2bf(f0.w);
        v[i][4] = f2bf(f1.x); v[i][5] = f2bf(f1.y);
        v[i][6] = f2bf(f1.z); v[i][7] = f2bf(f1.w);
    }
#pragma unroll
    for (int j = 0; j < 8; ++j) {
        U16x8 o;
#pragma unroll
        for (int i = 0; i < 8; ++i) o.u[i] = v[i][j];
        const int srow = s0 + j;
        const int off = srow * 64 + (((c0 >> 3) ^ (srow & 7)) << 3);
        *(U16x8*)(dst + off) = o;
    }
}

// Kernel A: ONE WAVE = ONE PAIR. 576 blocks x 4 independent waves = 2304
// pairs; zero barriers, zero LDS, zero cross-wave coupling — the R9-R12
// plateau was lockstep waves stalling at shared barriers 9x/block.
// rt-outer / ct-inner loops fully unrolled with constexpr window tables:
// exactly the 78 needed tiles are emitted straight-line, branch-free.
//   s2 (keep row): per-rt running max over ct in win(rt) -> rowmax16 (DPP).
//   s1 (keep col): per-ct quad-partial col-max in registers s1p[16];
//                  epilogue: cross-quad max via 2 shfl_xor, fc accumulate.
// acc.i = score(r = rt*16 + q*4 + i, s = ct*16 + laneM).
__global__ __launch_bounds__(256) void score_pam_kernel(
    const unsigned short* __restrict__ preT,  // [96][16384] bf16 pre-transposed
    const float* __restrict__ fcw,            // [256] f32
    float* __restrict__ outDot,               // [2304]
    float* __restrict__ outSum,               // [2304]
    float* __restrict__ outSq)                // [2304]
{
    constexpr int cLOW[16] = {0,0,0,1,2,3,4,5,6,7,8,9,10,11,12,12};
    constexpr int cHIW[16] = {3,3,3,4,5,6,7,8,9,10,11,12,13,14,15,15};

    const int tid = threadIdx.x;
    const int w = tid >> 6;
    const int lane = tid & 63;
    const int pair = blockIdx.x * 4 + w;       // 0..2303
    const int ip = pair / 48;
    const int ig = pair % 48;
    const unsigned short* pimg = preT + ip * 16384;         // B: probe (cols)
    const unsigned short* gimg = preT + (48 + ig) * 16384;  // A: gallery (rows)

    const int laneM = lane & 15;
    const int q = lane >> 4;
    const int z = laneM & 7;
    const int ch0 = (q ^ z) << 3;
    const int ch1 = ((q + 4) ^ z) << 3;

    float dot = 0.f, sum = 0.f, sq = 0.f;
    const float msk = (laneM == 0) ? 1.0f : 0.0f;   // one lane per s2 row copy
    const float msk1 = (q == 0) ? 1.0f : 0.0f;      // one quad per s1 col copy

    float s1p[16];
#pragma unroll
    for (int i = 0; i < 16; ++i) s1p[i] = -3.0e38f;

#pragma unroll
    for (int rt = 0; rt < 16; ++rt) {
        const int srow = rt * 16 + laneM;
        const short8 a0 = *(const short8*)(gimg + srow * 64 + ch0);
        const short8 a1 = *(const short8*)(gimg + srow * 64 + ch1);

        float4v run = { -3.0e38f, -3.0e38f, -3.0e38f, -3.0e38f };
#pragma unroll
        for (int ct = 0; ct < 16; ++ct) {
            // compile-time conditions: only the 78 union tiles are emitted
            const bool c2 = (ct >= cLOW[rt]) && (ct <= cHIW[rt]);  // hc in win(hr)
            const bool c1 = (rt >= cLOW[ct]) && (rt <= cHIW[ct]);  // hr in win(hc)
            if (c1 || c2) {
                const int sl = ct * 16 + laneM;
                const short8 b0 = *(const short8*)(pimg + sl * 64 + ch0);
                const short8 b1 = *(const short8*)(pimg + sl * 64 + ch1);
                float4v acc = { 0.f, 0.f, 0.f, 0.f };
                acc = __builtin_amdgcn_mfma_f32_16x16x32_bf16(a0, b0, acc, 0, 0, 0);
                acc = __builtin_amdgcn_mfma_f32_16x16x32_bf16(a1, b1, acc, 0, 0, 0);
                if (c2) {   // s2: per-row running max
                    run.x = fmaxf(run.x, acc.x);
                    run.y = fmaxf(run.y, acc.y);
                    run.z = fmaxf(run.z, acc.z);
                    run.w = fmaxf(run.w, acc.w);
                }
                if (c1) {   // s1: quad-partial col-max (compile-time reg index)
                    const float t = fmaxf(fmaxf(acc.x, acc.y), fmaxf(acc.z, acc.w));
                    s1p[ct] = fmaxf(s1p[ct], t);
                }
            }
        }
        // s2 epilogue for this rt: DPP row-max + masked accumulate
        const float rx = rowmax16(run.x);
        const float ry = rowmax16(run.y);
        const float rz = rowmax16(run.z);
        const float rw = rowmax16(run.w);
        const float4v fw = *(const float4v*)(fcw + rt * 16 + q * 4);
        float t;
        t = msk * rx; dot += t * fw.x; sum += t; sq += t * rx;
        t = msk * ry; dot += t * fw.y; sum += t; sq += t * ry;
        t = msk * rz; dot += t * fw.z; sum += t; sq += t * rz;
        t = msk * rw; dot += t * fw.w; sum += t; sq += t * rw;
    }

    // ---- s1 epilogue: cross-quad max (shfl over 16/32), masked accumulate
#pragma unroll
    for (int ct = 0; ct < 16; ++ct) {
        float v = s1p[ct];
        v = fmaxf(v, __shfl_xor(v, 16, 64));
        v = fmaxf(v, __shfl_xor(v, 32, 64));   // col-max for s = ct*16 + laneM
        const float fv = fcw[ct * 16 + laneM];
        const float tt = msk1 * v;
        dot += tt * fv; sum += tt; sq += tt * v;
    }

    // ---- full-wave sum of the 3 scalars; lane 0 stores (per-wave outputs)
    dot = rowsum16(dot); dot += __shfl_xor(dot, 16, 64); dot += __shfl_xor(dot, 32, 64);
    sum = rowsum16(sum); sum += __shfl_xor(sum, 16, 64); sum += __shfl_xor(sum, 32, 64);
    sq  = rowsum16(sq);  sq  += __shfl_xor(sq, 16, 64);  sq  += __shfl_xor(sq, 32, 64);
    if (lane == 0) {
        outDot[pair] = dot;
        outSum[pair] = sum;
        outSq[pair] = sq;
    }
}

// Kernel B: single block. Global BN1 stats from per-pair sums, fc (linear),
// pair-sum, BN2 over 2304, sigmoid, f32 store.
__global__ __launch_bounds__(256) void finalize_kernel(
    const float* __restrict__ dDot,
    const float* __restrict__ dSum,
    const float* __restrict__ dSq,
    const float* __restrict__ bng,
    const float* __restrict__ bnb,
    const float* __restrict__ fcw,
    const float* __restrict__ fcb,
    const float* __restrict__ lg,
    const float* __restrict__ lb,
    float* __restrict__ outp)   // [2304] f32
{
    __shared__ float red[12];
    const int tid = threadIdx.x;
    const int lane = tid & 63;
    const int w = tid >> 6;

    float S = 0.f, Q = 0.f;
    float dv[9];
#pragma unroll
    for (int k = 0; k < 9; ++k) {
        const int i = tid + 256 * k;
        dv[k] = dDot[i];
        S += dSum[i];
        Q += dSq[i];
    }
    float Wj = fcw[tid];
#pragma unroll
    for (int d = 32; d >= 1; d >>= 1) {
        S += __shfl_down(S, d, 64);
        Q += __shfl_down(Q, d, 64);
        Wj += __shfl_down(Wj, d, 64);
    }
    if (lane == 0) { red[w] = S; red[4 + w] = Q; red[8 + w] = Wj; }
    __syncthreads();
    S = red[0] + red[1] + red[2] + red[3];
    Q = red[4] + red[5] + red[6] + red[7];
    const float W = red[8] + red[9] + red[10] + red[11];
    __syncthreads();

    const float N1 = 1179648.0f;           // 4608 * 256 elements in BN1
    const float m1 = S / N1;
    const float v1 = Q / N1 - m1 * m1;     // biased var (torch training default)
    const float inv1 = rsqrtf(v1 + 1e-5f);
    const float g1 = bng[0], b1 = bnb[0], fb = fcb[0];
    const float g2 = lg[0], b2 = lb[0];
    const float cA = g1 * inv1;
    const float cB = 2.f * (b1 * W + fb) - cA * 2.f * m1 * W;

    float Sy = 0.f, Qy = 0.f;
    float yv[9];
#pragma unroll
    for (int k = 0; k < 9; ++k) {
        const float y = cA * dv[k] + cB;
        yv[k] = y;
        Sy += y;
        Qy += y * y;
    }
#pragma unroll
    for (int d = 32; d >= 1; d >>= 1) {
        Sy += __shfl_down(Sy, d, 64);
        Qy += __shfl_down(Qy, d, 64);
    }
    if (lane == 0) { red[w] = Sy; red[4 + w] = Qy; }
    __syncthreads();
    Sy = red[0] + red[1] + red[2] + red[3];
    Qy = red[4] + red[5] + red[6] + red[7];

    const float m2 = Sy / 2304.0f;
    const float v2 = Qy / 2304.0f - m2 * m2;
    const float inv2 = rsqrtf(v2 + 1e-5f);
#pragma unroll
    for (int k = 0; k < 9; ++k) {
        const int i = tid + 256 * k;
        const float z = g2 * (yv[k] - m2) * inv2 + b2;
        outp[i] = 1.0f / (1.0f + __expf(-z));
    }
}

extern "C" void kernel_launch(void* const* d_in, const int* in_sizes, int n_in,
                              void* d_out, int out_size, void* d_ws, size_t ws_size,
                              hipStream_t stream) {
    const float* prob = (const float*)d_in[0];
    const float* gal  = (const float*)d_in[1];
    const float* bng  = (const float*)d_in[2];
    const float* bnb  = (const float*)d_in[3];
    const float* fcw  = (const float*)d_in[4];
    const float* fcb  = (const float*)d_in[5];
    const float* lg   = (const float*)d_in[6];
    const float* lb   = (const float*)d_in[7];

    unsigned short* preT = (unsigned short*)d_ws;        // 96*16384 bf16 = 3 MB
    float* ws = (float*)((char*)d_ws + 96 * 16384 * sizeof(unsigned short));
    float* dDot = ws;            // [2304]
    float* dSum = ws + 2304;     // [2304]
    float* dSq  = ws + 4608;     // [2304]

    hipLaunchKernelGGL(pretranspose_kernel, dim3(384), dim3(64), 0, stream,
                       prob, gal, preT);
    hipLaunchKernelGGL(score_pam_kernel, dim3(576), dim3(256), 0, stream,
                       preT, fcw, dDot, dSum, dSq);
    hipLaunchKernelGGL(finalize_kernel, dim3(1), dim3(256), 0, stream,
                       dDot, dSum, dSq, bng, bnb, fcw, fcb, lg, lb,
                       (float*)d_out);
}

// Round 14
// 94.798 us; speedup vs baseline: 1.0839x; 1.0060x over previous
//
#include <hip/hip_runtime.h>

typedef __attribute__((ext_vector_type(8))) short short8;
typedef __attribute__((ext_vector_type(4))) float float4v;

__device__ __forceinline__ unsigned short f2bf(float f) {
    unsigned int x = __builtin_bit_cast(unsigned int, f);
    x += 0x7FFF + ((x >> 16) & 1);   // round-to-nearest-even
    return (unsigned short)(x >> 16);
}

struct __align__(16) U16x8 { unsigned short u[8]; };

// DPP cross-lane ops within 16-lane rows — pure VALU.
template <int CTRL>
__device__ __forceinline__ float dppmaxf(float x) {
    int y = __builtin_amdgcn_update_dpp(0, __builtin_bit_cast(int, x),
                                        CTRL, 0xF, 0xF, true);
    return fmaxf(x, __builtin_bit_cast(float, y));
}
template <int CTRL>
__device__ __forceinline__ float dppaddf(float x) {
    int y = __builtin_amdgcn_update_dpp(0, __builtin_bit_cast(int, x),
                                        CTRL, 0xF, 0xF, true);
    return x + __builtin_bit_cast(float, y);
}
__device__ __forceinline__ float rowmax16(float x) {
    x = dppmaxf<0xB1>(x);    // quad_perm [1,0,3,2]
    x = dppmaxf<0x4E>(x);    // quad_perm [2,3,0,1]
    x = dppmaxf<0x141>(x);   // row_half_mirror
    x = dppmaxf<0x140>(x);   // row_mirror
    return x;
}
__device__ __forceinline__ float rowsum16(float x) {
    x = dppaddf<0xB1>(x);
    x = dppaddf<0x4E>(x);
    x = dppaddf<0x141>(x);
    x = dppaddf<0x140>(x);
    return x;
}

// Kernel 0: f32 [img][64c][256s] -> bf16 [img][s][c] with chunk XOR swizzle
// (chunk' = (c/8) ^ (s%8)). imgs 0..47 = probe, 48..95 = gallery.
// 384 single-wave blocks: img = bid>>2, s-quarter = bid&3.
__global__ __launch_bounds__(64) void pretranspose_kernel(
    const float* __restrict__ prob,
    const float* __restrict__ gal,
    unsigned short* __restrict__ outT)   // [96][16384] bf16
{
    const int img = blockIdx.x >> 2;
    const int quarter = blockIdx.x & 3;
    const float* src = (img < 48) ? (prob + img * 16384)
                                  : (gal + (img - 48) * 16384);
    unsigned short* dst = outT + img * 16384;
    const int tid = threadIdx.x;          // 0..63
    const int c0 = (tid & 7) * 8;
    const int s0 = quarter * 64 + (tid >> 3) * 8;
    unsigned short v[8][8];
#pragma unroll
    for (int i = 0; i < 8; ++i) {
        const float* p = src + (c0 + i) * 256 + s0;
        const float4v f0 = *(const float4v*)(p);
        const float4v f1 = *(const float4v*)(p + 4);
        v[i][0] = f2bf(f0.x); v[i][1] = f2bf(f0.y);
        v[i][2] = f2bf(f0.z); v[i][3] = f2bf(f0.w);
        v[i][4] = f2bf(f1.x); v[i][5] = f2bf(f1.y);
        v[i][6] = f2bf(f1.z); v[i][7] = f2bf(f1.w);
    }
#pragma unroll
    for (int j = 0; j < 8; ++j) {
        U16x8 o;
#pragma unroll
        for (int i = 0; i < 8; ++i) o.u[i] = v[i][j];
        const int srow = s0 + j;
        const int off = srow * 64 + (((c0 >> 3) ^ (srow & 7)) << 3);
        *(U16x8*)(dst + off) = o;
    }
}

// Kernel A: ONE WAVE = ONE PAIR = ONE BLOCK. Grid 2304 x 64: exactly 9
// single-wave blocks per CU — perfectly balanced (R13's 576x4-wave grid put
// 3 blocks on 64 CUs and 2 on the rest: a structural 1.33x tail).
// Pair remap (bijection): pair = (bid&255)*9 + (bid>>8) — bids 256 apart
// (which the dispatcher tends to co-locate on a CU) share ONE probe image, so
// the 32 KB probe fits the CU's 32 KB L1 and 8/9 waves' B-loads are L1 hits.
// Branch-free body: rt/ct loops fully unrolled over the 78 needed tiles,
// zero barriers, zero LDS. acc.i = score(r = rt*16+q*4+i, s = ct*16+laneM).
__global__ __launch_bounds__(64) void score_pam_kernel(
    const unsigned short* __restrict__ preT,  // [96][16384] bf16 pre-transposed
    const float* __restrict__ fcw,            // [256] f32
    float* __restrict__ outDot,               // [2304]
    float* __restrict__ outSum,               // [2304]
    float* __restrict__ outSq)                // [2304]
{
    constexpr int cLOW[16] = {0,0,0,1,2,3,4,5,6,7,8,9,10,11,12,12};
    constexpr int cHIW[16] = {3,3,3,4,5,6,7,8,9,10,11,12,13,14,15,15};

    const int lane = threadIdx.x;              // 0..63 (one wave)
    const int bid = blockIdx.x;                // 0..2303
    const int pair = (bid & 255) * 9 + (bid >> 8);   // CU-affine bijection
    const int ip = pair / 48;
    const int ig = pair % 48;
    const unsigned short* pimg = preT + ip * 16384;         // B: probe (cols)
    const unsigned short* gimg = preT + (48 + ig) * 16384;  // A: gallery (rows)

    const int laneM = lane & 15;
    const int q = lane >> 4;
    const int z = laneM & 7;
    const int ch0 = (q ^ z) << 3;
    const int ch1 = ((q + 4) ^ z) << 3;

    float dot = 0.f, sum = 0.f, sq = 0.f;
    const float msk = (laneM == 0) ? 1.0f : 0.0f;   // one lane per s2 row copy
    const float msk1 = (q == 0) ? 1.0f : 0.0f;      // one quad per s1 col copy

    float s1p[16];
#pragma unroll
    for (int i = 0; i < 16; ++i) s1p[i] = -3.0e38f;

#pragma unroll
    for (int rt = 0; rt < 16; ++rt) {
        const int srow = rt * 16 + laneM;
        const short8 a0 = *(const short8*)(gimg + srow * 64 + ch0);
        const short8 a1 = *(const short8*)(gimg + srow * 64 + ch1);

        float4v run = { -3.0e38f, -3.0e38f, -3.0e38f, -3.0e38f };
#pragma unroll
        for (int ct = 0; ct < 16; ++ct) {
            // compile-time conditions: only the 78 union tiles are emitted
            const bool c2 = (ct >= cLOW[rt]) && (ct <= cHIW[rt]);  // hc in win(hr)
            const bool c1 = (rt >= cLOW[ct]) && (rt <= cHIW[ct]);  // hr in win(hc)
            if (c1 || c2) {
                const int sl = ct * 16 + laneM;
                const short8 b0 = *(const short8*)(pimg + sl * 64 + ch0);
                const short8 b1 = *(const short8*)(pimg + sl * 64 + ch1);
                float4v acc = { 0.f, 0.f, 0.f, 0.f };
                acc = __builtin_amdgcn_mfma_f32_16x16x32_bf16(a0, b0, acc, 0, 0, 0);
                acc = __builtin_amdgcn_mfma_f32_16x16x32_bf16(a1, b1, acc, 0, 0, 0);
                if (c2) {   // s2: per-row running max
                    run.x = fmaxf(run.x, acc.x);
                    run.y = fmaxf(run.y, acc.y);
                    run.z = fmaxf(run.z, acc.z);
                    run.w = fmaxf(run.w, acc.w);
                }
                if (c1) {   // s1: quad-partial col-max (compile-time reg index)
                    const float t = fmaxf(fmaxf(acc.x, acc.y), fmaxf(acc.z, acc.w));
                    s1p[ct] = fmaxf(s1p[ct], t);
                }
            }
        }
        // s2 epilogue for this rt: DPP row-max + masked accumulate
        const float rx = rowmax16(run.x);
        const float ry = rowmax16(run.y);
        const float rz = rowmax16(run.z);
        const float rw = rowmax16(run.w);
        const float4v fw = *(const float4v*)(fcw + rt * 16 + q * 4);
        float t;
        t = msk * rx; dot += t * fw.x; sum += t; sq += t * rx;
        t = msk * ry; dot += t * fw.y; sum += t; sq += t * ry;
        t = msk * rz; dot += t * fw.z; sum += t; sq += t * rz;
        t = msk * rw; dot += t * fw.w; sum += t; sq += t * rw;
    }

    // ---- s1 epilogue: cross-quad max (shfl over 16/32), masked accumulate
#pragma unroll
    for (int ct = 0; ct < 16; ++ct) {
        float v = s1p[ct];
        v = fmaxf(v, __shfl_xor(v, 16, 64));
        v = fmaxf(v, __shfl_xor(v, 32, 64));   // col-max for s = ct*16 + laneM
        const float fv = fcw[ct * 16 + laneM];
        const float tt = msk1 * v;
        dot += tt * fv; sum += tt; sq += tt * v;
    }

    // ---- full-wave sum of the 3 scalars; lane 0 stores
    dot = rowsum16(dot); dot += __shfl_xor(dot, 16, 64); dot += __shfl_xor(dot, 32, 64);
    sum = rowsum16(sum); sum += __shfl_xor(sum, 16, 64); sum += __shfl_xor(sum, 32, 64);
    sq  = rowsum16(sq);  sq  += __shfl_xor(sq, 16, 64);  sq  += __shfl_xor(sq, 32, 64);
    if (lane == 0) {
        outDot[pair] = dot;
        outSum[pair] = sum;
        outSq[pair] = sq;
    }
}

// Kernel B: single block. Global BN1 stats from per-pair sums, fc (linear),
// pair-sum, BN2 over 2304, sigmoid, f32 store.
__global__ __launch_bounds__(256) void finalize_kernel(
    const float* __restrict__ dDot,
    const float* __restrict__ dSum,
    const float* __restrict__ dSq,
    const float* __restrict__ bng,
    const float* __restrict__ bnb,
    const float* __restrict__ fcw,
    const float* __restrict__ fcb,
    const float* __restrict__ lg,
    const float* __restrict__ lb,
    float* __restrict__ outp)   // [2304] f32
{
    __shared__ float red[12];
    const int tid = threadIdx.x;
    const int lane = tid & 63;
    const int w = tid >> 6;

    float S = 0.f, Q = 0.f;
    float dv[9];
#pragma unroll
    for (int k = 0; k < 9; ++k) {
        const int i = tid + 256 * k;
        dv[k] = dDot[i];
        S += dSum[i];
        Q += dSq[i];
    }
    float Wj = fcw[tid];
#pragma unroll
    for (int d = 32; d >= 1; d >>= 1) {
        S += __shfl_down(S, d, 64);
        Q += __shfl_down(Q, d, 64);
        Wj += __shfl_down(Wj, d, 64);
    }
    if (lane == 0) { red[w] = S; red[4 + w] = Q; red[8 + w] = Wj; }
    __syncthreads();
    S = red[0] + red[1] + red[2] + red[3];
    Q = red[4] + red[5] + red[6] + red[7];
    const float W = red[8] + red[9] + red[10] + red[11];
    __syncthreads();

    const float N1 = 1179648.0f;           // 4608 * 256 elements in BN1
    const float m1 = S / N1;
    const float v1 = Q / N1 - m1 * m1;     // biased var (torch training default)
    const float inv1 = rsqrtf(v1 + 1e-5f);
    const float g1 = bng[0], b1 = bnb[0], fb = fcb[0];
    const float g2 = lg[0], b2 = lb[0];
    const float cA = g1 * inv1;
    const float cB = 2.f * (b1 * W + fb) - cA * 2.f * m1 * W;

    float Sy = 0.f, Qy = 0.f;
    float yv[9];
#pragma unroll
    for (int k = 0; k < 9; ++k) {
        const float y = cA * dv[k] + cB;
        yv[k] = y;
        Sy += y;
        Qy += y * y;
    }
#pragma unroll
    for (int d = 32; d >= 1; d >>= 1) {
        Sy += __shfl_down(Sy, d, 64);
        Qy += __shfl_down(Qy, d, 64);
    }
    if (lane == 0) { red[w] = Sy; red[4 + w] = Qy; }
    __syncthreads();
    Sy = red[0] + red[1] + red[2] + red[3];
    Qy = red[4] + red[5] + red[6] + red[7];

    const float m2 = Sy / 2304.0f;
    const float v2 = Qy / 2304.0f - m2 * m2;
    const float inv2 = rsqrtf(v2 + 1e-5f);
#pragma unroll
    for (int k = 0; k < 9; ++k) {
        const int i = tid + 256 * k;
        const float z = g2 * (yv[k] - m2) * inv2 + b2;
        outp[i] = 1.0f / (1.0f + __expf(-z));
    }
}

extern "C" void kernel_launch(void* const* d_in, const int* in_sizes, int n_in,
                              void* d_out, int out_size, void* d_ws, size_t ws_size,
                              hipStream_t stream) {
    const float* prob = (const float*)d_in[0];
    const float* gal  = (const float*)d_in[1];
    const float* bng  = (const float*)d_in[2];
    const float* bnb  = (const float*)d_in[3];
    const float* fcw  = (const float*)d_in[4];
    const float* fcb  = (const float*)d_in[5];
    const float* lg   = (const float*)d_in[6];
    const float* lb   = (const float*)d_in[7];

    unsigned short* preT = (unsigned short*)d_ws;        // 96*16384 bf16 = 3 MB
    float* ws = (float*)((char*)d_ws + 96 * 16384 * sizeof(unsigned short));
    float* dDot = ws;            // [2304]
    float* dSum = ws + 2304;     // [2304]
    float* dSq  = ws + 4608;     // [2304]

    hipLaunchKernelGGL(pretranspose_kernel, dim3(384), dim3(64), 0, stream,
                       prob, gal, preT);
    hipLaunchKernelGGL(score_pam_kernel, dim3(2304), dim3(64), 0, stream,
                       preT, fcw, dDot, dSum, dSq);
    hipLaunchKernelGGL(finalize_kernel, dim3(1), dim3(256), 0, stream,
                       dDot, dSum, dSq, bng, bnb, fcw, fcb, lg, lb,
                       (float*)d_out);
}

// Round 15
// 93.441 us; speedup vs baseline: 1.0997x; 1.0145x over previous
//
#include <hip/hip_runtime.h>

typedef __attribute__((ext_vector_type(8))) short short8;
typedef __attribute__((ext_vector_type(4))) float float4v;

__device__ __forceinline__ unsigned short f2bf(float f) {
    unsigned int x = __builtin_bit_cast(unsigned int, f);
    x += 0x7FFF + ((x >> 16) & 1);   // round-to-nearest-even
    return (unsigned short)(x >> 16);
}

struct __align__(16) U16x8 { unsigned short u[8]; };

// DPP cross-lane ops within 16-lane rows — pure VALU.
template <int CTRL>
__device__ __forceinline__ float dppmaxf(float x) {
    int y = __builtin_amdgcn_update_dpp(0, __builtin_bit_cast(int, x),
                                        CTRL, 0xF, 0xF, true);
    return fmaxf(x, __builtin_bit_cast(float, y));
}
template <int CTRL>
__device__ __forceinline__ float dppaddf(float x) {
    int y = __builtin_amdgcn_update_dpp(0, __builtin_bit_cast(int, x),
                                        CTRL, 0xF, 0xF, true);
    return x + __builtin_bit_cast(float, y);
}
__device__ __forceinline__ float rowmax16(float x) {
    x = dppmaxf<0xB1>(x);    // quad_perm [1,0,3,2]
    x = dppmaxf<0x4E>(x);    // quad_perm [2,3,0,1]
    x = dppmaxf<0x141>(x);   // row_half_mirror
    x = dppmaxf<0x140>(x);   // row_mirror
    return x;
}
__device__ __forceinline__ float rowsum16(float x) {
    x = dppaddf<0xB1>(x);
    x = dppaddf<0x4E>(x);
    x = dppaddf<0x141>(x);
    x = dppaddf<0x140>(x);
    return x;
}

// Kernel 0: f32 [img][64c][256s] -> bf16 [img][s][c] with chunk XOR swizzle
// (chunk' = (c/8) ^ (s%8)). imgs 0..47 = probe, 48..95 = gallery.
// 384 single-wave blocks: img = bid>>2, s-quarter = bid&3.
__global__ __launch_bounds__(64) void pretranspose_kernel(
    const float* __restrict__ prob,
    const float* __restrict__ gal,
    unsigned short* __restrict__ outT)   // [96][16384] bf16
{
    const int img = blockIdx.x >> 2;
    const int quarter = blockIdx.x & 3;
    const float* src = (img < 48) ? (prob + img * 16384)
                                  : (gal + (img - 48) * 16384);
    unsigned short* dst = outT + img * 16384;
    const int tid = threadIdx.x;          // 0..63
    const int c0 = (tid & 7) * 8;
    const int s0 = quarter * 64 + (tid >> 3) * 8;
    unsigned short v[8][8];
#pragma unroll
    for (int i = 0; i < 8; ++i) {
        const float* p = src + (c0 + i) * 256 + s0;
        const float4v f0 = *(const float4v*)(p);
        const float4v f1 = *(const float4v*)(p + 4);
        v[i][0] = f2bf(f0.x); v[i][1] = f2bf(f0.y);
        v[i][2] = f2bf(f0.z); v[i][3] = f2bf(f0.w);
        v[i][4] = f2bf(f1.x); v[i][5] = f2bf(f1.y);
        v[i][6] = f2bf(f1.z); v[i][7] = f2bf(f1.w);
    }
#pragma unroll
    for (int j = 0; j < 8; ++j) {
        U16x8 o;
#pragma unroll
        for (int i = 0; i < 8; ++i) o.u[i] = v[i][j];
        const int srow = s0 + j;
        const int off = srow * 64 + (((c0 >> 3) ^ (srow & 7)) << 3);
        *(U16x8*)(dst + off) = o;
    }
}

// Kernel A: ONE WAVE = ONE PAIR, with the ENTIRE PROBE IMAGE held in
// registers: 32 KB = 512 B/lane = 128 VGPRs (B0[16]+B1[16] short8).
// R14's wave read the probe ~5x through L1 (156 B-loads, 204 KB/wave of L1
// data traffic — the measured binding term). Now: 32 independent up-front
// loads (max MLP, no spill: ~180 live VGPRs under the 256 cap of
// __launch_bounds__(64,2)), then the 78-tile body is register-fed.
// Branch-free full unroll, zero LDS, zero barriers.
// acc.i = score(r = rt*16+q*4+i, s = ct*16+laneM).
__global__ __launch_bounds__(64, 2) void score_pam_kernel(
    const unsigned short* __restrict__ preT,  // [96][16384] bf16 pre-transposed
    const float* __restrict__ fcw,            // [256] f32
    float* __restrict__ outDot,               // [2304]
    float* __restrict__ outSum,               // [2304]
    float* __restrict__ outSq)                // [2304]
{
    constexpr int cLOW[16] = {0,0,0,1,2,3,4,5,6,7,8,9,10,11,12,12};
    constexpr int cHIW[16] = {3,3,3,4,5,6,7,8,9,10,11,12,13,14,15,15};

    const int lane = threadIdx.x;              // 0..63 (one wave)
    const int bid = blockIdx.x;                // 0..2303
    const int pair = (bid & 255) * 9 + (bid >> 8);   // CU-affine bijection
    const int ip = pair / 48;
    const int ig = pair % 48;
    const unsigned short* pimg = preT + ip * 16384;         // B: probe (cols)
    const unsigned short* gimg = preT + (48 + ig) * 16384;  // A: gallery (rows)

    const int laneM = lane & 15;
    const int q = lane >> 4;
    const int z = laneM & 7;
    const int ch0 = (q ^ z) << 3;
    const int ch1 = ((q + 4) ^ z) << 3;

    // ---- register-resident probe: 32 independent loads, 128 VGPRs
    short8 B0[16], B1[16];
#pragma unroll
    for (int ct = 0; ct < 16; ++ct) {
        const int sl = ct * 16 + laneM;
        B0[ct] = *(const short8*)(pimg + sl * 64 + ch0);
        B1[ct] = *(const short8*)(pimg + sl * 64 + ch1);
    }

    float dot = 0.f, sum = 0.f, sq = 0.f;
    const float msk = (laneM == 0) ? 1.0f : 0.0f;   // one lane per s2 row copy
    const float msk1 = (q == 0) ? 1.0f : 0.0f;      // one quad per s1 col copy

    float s1p[16];
#pragma unroll
    for (int i = 0; i < 16; ++i) s1p[i] = -3.0e38f;

#pragma unroll
    for (int rt = 0; rt < 16; ++rt) {
        const int srow = rt * 16 + laneM;
        const short8 a0 = *(const short8*)(gimg + srow * 64 + ch0);
        const short8 a1 = *(const short8*)(gimg + srow * 64 + ch1);

        float4v run = { -3.0e38f, -3.0e38f, -3.0e38f, -3.0e38f };
#pragma unroll
        for (int ct = 0; ct < 16; ++ct) {
            // compile-time conditions: only the 78 union tiles are emitted
            const bool c2 = (ct >= cLOW[rt]) && (ct <= cHIW[rt]);  // hc in win(hr)
            const bool c1 = (rt >= cLOW[ct]) && (rt <= cHIW[ct]);  // hr in win(hc)
            if (c1 || c2) {
                float4v acc = { 0.f, 0.f, 0.f, 0.f };
                acc = __builtin_amdgcn_mfma_f32_16x16x32_bf16(a0, B0[ct], acc, 0, 0, 0);
                acc = __builtin_amdgcn_mfma_f32_16x16x32_bf16(a1, B1[ct], acc, 0, 0, 0);
                if (c2) {   // s2: per-row running max
                    run.x = fmaxf(run.x, acc.x);
                    run.y = fmaxf(run.y, acc.y);
                    run.z = fmaxf(run.z, acc.z);
                    run.w = fmaxf(run.w, acc.w);
                }
                if (c1) {   // s1: quad-partial col-max (compile-time reg index)
                    const float t = fmaxf(fmaxf(acc.x, acc.y), fmaxf(acc.z, acc.w));
                    s1p[ct] = fmaxf(s1p[ct], t);
                }
            }
        }
        // s2 epilogue for this rt: DPP row-max + masked accumulate
        const float rx = rowmax16(run.x);
        const float ry = rowmax16(run.y);
        const float rz = rowmax16(run.z);
        const float rw = rowmax16(run.w);
        const float4v fw = *(const float4v*)(fcw + rt * 16 + q * 4);
        float t;
        t = msk * rx; dot += t * fw.x; sum += t; sq += t * rx;
        t = msk * ry; dot += t * fw.y; sum += t; sq += t * ry;
        t = msk * rz; dot += t * fw.z; sum += t; sq += t * rz;
        t = msk * rw; dot += t * fw.w; sum += t; sq += t * rw;
    }

    // ---- s1 epilogue: cross-quad max (shfl over 16/32), masked accumulate
#pragma unroll
    for (int ct = 0; ct < 16; ++ct) {
        float v = s1p[ct];
        v = fmaxf(v, __shfl_xor(v, 16, 64));
        v = fmaxf(v, __shfl_xor(v, 32, 64));   // col-max for s = ct*16 + laneM
        const float fv = fcw[ct * 16 + laneM];
        const float tt = msk1 * v;
        dot += tt * fv; sum += tt; sq += tt * v;
    }

    // ---- full-wave sum of the 3 scalars; lane 0 stores
    dot = rowsum16(dot); dot += __shfl_xor(dot, 16, 64); dot += __shfl_xor(dot, 32, 64);
    sum = rowsum16(sum); sum += __shfl_xor(sum, 16, 64); sum += __shfl_xor(sum, 32, 64);
    sq  = rowsum16(sq);  sq  += __shfl_xor(sq, 16, 64);  sq  += __shfl_xor(sq, 32, 64);
    if (lane == 0) {
        outDot[pair] = dot;
        outSum[pair] = sum;
        outSq[pair] = sq;
    }
}

// Kernel B: single block. Global BN1 stats from per-pair sums, fc (linear),
// pair-sum, BN2 over 2304, sigmoid, f32 store.
__global__ __launch_bounds__(256) void finalize_kernel(
    const float* __restrict__ dDot,
    const float* __restrict__ dSum,
    const float* __restrict__ dSq,
    const float* __restrict__ bng,
    const float* __restrict__ bnb,
    const float* __restrict__ fcw,
    const float* __restrict__ fcb,
    const float* __restrict__ lg,
    const float* __restrict__ lb,
    float* __restrict__ outp)   // [2304] f32
{
    __shared__ float red[12];
    const int tid = threadIdx.x;
    const int lane = tid & 63;
    const int w = tid >> 6;

    float S = 0.f, Q = 0.f;
    float dv[9];
#pragma unroll
    for (int k = 0; k < 9; ++k) {
        const int i = tid + 256 * k;
        dv[k] = dDot[i];
        S += dSum[i];
        Q += dSq[i];
    }
    float Wj = fcw[tid];
#pragma unroll
    for (int d = 32; d >= 1; d >>= 1) {
        S += __shfl_down(S, d, 64);
        Q += __shfl_down(Q, d, 64);
        Wj += __shfl_down(Wj, d, 64);
    }
    if (lane == 0) { red[w] = S; red[4 + w] = Q; red[8 + w] = Wj; }
    __syncthreads();
    S = red[0] + red[1] + red[2] + red[3];
    Q = red[4] + red[5] + red[6] + red[7];
    const float W = red[8] + red[9] + red[10] + red[11];
    __syncthreads();

    const float N1 = 1179648.0f;           // 4608 * 256 elements in BN1
    const float m1 = S / N1;
    const float v1 = Q / N1 - m1 * m1;     // biased var (torch training default)
    const float inv1 = rsqrtf(v1 + 1e-5f);
    const float g1 = bng[0], b1 = bnb[0], fb = fcb[0];
    const float g2 = lg[0], b2 = lb[0];
    const float cA = g1 * inv1;
    const float cB = 2.f * (b1 * W + fb) - cA * 2.f * m1 * W;

    float Sy = 0.f, Qy = 0.f;
    float yv[9];
#pragma unroll
    for (int k = 0; k < 9; ++k) {
        const float y = cA * dv[k] + cB;
        yv[k] = y;
        Sy += y;
        Qy += y * y;
    }
#pragma unroll
    for (int d = 32; d >= 1; d >>= 1) {
        Sy += __shfl_down(Sy, d, 64);
        Qy += __shfl_down(Qy, d, 64);
    }
    if (lane == 0) { red[w] = Sy; red[4 + w] = Qy; }
    __syncthreads();
    Sy = red[0] + red[1] + red[2] + red[3];
    Qy = red[4] + red[5] + red[6] + red[7];

    const float m2 = Sy / 2304.0f;
    const float v2 = Qy / 2304.0f - m2 * m2;
    const float inv2 = rsqrtf(v2 + 1e-5f);
#pragma unroll
    for (int k = 0; k < 9; ++k) {
        const int i = tid + 256 * k;
        const float z = g2 * (yv[k] - m2) * inv2 + b2;
        outp[i] = 1.0f / (1.0f + __expf(-z));
    }
}

extern "C" void kernel_launch(void* const* d_in, const int* in_sizes, int n_in,
                              void* d_out, int out_size, void* d_ws, size_t ws_size,
                              hipStream_t stream) {
    const float* prob = (const float*)d_in[0];
    const float* gal  = (const float*)d_in[1];
    const float* bng  = (const float*)d_in[2];
    const float* bnb  = (const float*)d_in[3];
    const float* fcw  = (const float*)d_in[4];
    const float* fcb  = (const float*)d_in[5];
    const float* lg   = (const float*)d_in[6];
    const float* lb   = (const float*)d_in[7];

    unsigned short* preT = (unsigned short*)d_ws;        // 96*16384 bf16 = 3 MB
    float* ws = (float*)((char*)d_ws + 96 * 16384 * sizeof(unsigned short));
    float* dDot = ws;            // [2304]
    float* dSum = ws + 2304;     // [2304]
    float* dSq  = ws + 4608;     // [2304]

    hipLaunchKernelGGL(pretranspose_kernel, dim3(384), dim3(64), 0, stream,
                       prob, gal, preT);
    hipLaunchKernelGGL(score_pam_kernel, dim3(2304), dim3(64), 0, stream,
                       preT, fcw, dDot, dSum, dSq);
    hipLaunchKernelGGL(finalize_kernel, dim3(1), dim3(256), 0, stream,
                       dDot, dSum, dSq, bng, bnb, fcw, fcb, lg, lb,
                       (float*)d_out);
}